// Round 5
// baseline (941.367 us; speedup 1.0000x reference)
//
#include <hip/hip_runtime.h>
#include <math.h>

#define PSPLIT 8
#define BSH 5                  // bucket = dst >> BSH  (32 dsts/bucket)
#define BW 32

typedef float f4v __attribute__((ext_vector_type(4)));

static inline size_t align_up(size_t x, size_t a){ return (x + a - 1) & ~(a - 1); }

// ---------------- graph prep: bucketed CSR build ----------------

__global__ __launch_bounds__(256) void k_bhist(const int* __restrict__ col, int* __restrict__ bcnt,
                                               int E, int NB,
                                               const int* __restrict__ batch, int* __restrict__ gstart,
                                               int n, int G){
  extern __shared__ int lh[];
  for (int i = threadIdx.x; i < NB; i += 256) lh[i] = 0;
  __syncthreads();
  for (int e = blockIdx.x * 256 + threadIdx.x; e < E; e += gridDim.x * 256)
    atomicAdd(&lh[col[e] >> BSH], 1);
  __syncthreads();
  for (int i = threadIdx.x; i < NB; i += 256){
    int v = lh[i];
    if (v) atomicAdd(&bcnt[i], v);
  }
  // fused gstart
  for (int i = blockIdx.x * 256 + threadIdx.x; i < n; i += gridDim.x * 256){
    int cb = batch[i];
    if (i == 0){ for (int g = 0; g <= cb; ++g) gstart[g] = 0; }
    else { int pb = batch[i - 1]; for (int g = pb + 1; g <= cb; ++g) gstart[g] = i; }
    if (i == n - 1){ for (int g = cb + 1; g <= G; ++g) gstart[g] = n; }
  }
}

__global__ void k_bscan(const int* __restrict__ bcnt, int* __restrict__ boff, int NB, int E,
                        int* __restrict__ rp, int N){
  __shared__ int sd[256];
  int t = threadIdx.x;
  int c[16]; int s = 0;
  const int PT = (NB + 255) / 256;   // <= 16
  for (int j = 0; j < PT; ++j){ int i = t * PT + j; c[j] = (i < NB) ? bcnt[i] : 0; s += c[j]; }
  sd[t] = s; __syncthreads();
  for (int off = 1; off < 256; off <<= 1){
    int v = sd[t];
    if (t >= off) v += sd[t - off];
    __syncthreads(); sd[t] = v; __syncthreads();
  }
  int run = sd[t] - s;
  for (int j = 0; j < PT; ++j){ int i = t * PT + j; if (i < NB) boff[i] = run; run += c[j]; }
  if (t == 255){ boff[NB] = run; rp[N] = E; }
}

__global__ __launch_bounds__(256) void k_bscat(const int* __restrict__ ei, const int* __restrict__ boff,
                                               int* __restrict__ bfill, unsigned* __restrict__ tmp, int E){
  int e = blockIdx.x * 256 + threadIdx.x;
  if (e >= E) return;
  int s = ei[e], d = ei[E + e];
  int b = d >> BSH;
  int p = atomicAdd(&bfill[b * 16], 1);          // line-padded counter
  tmp[boff[b] + p] = (unsigned)s | ((unsigned)(d & (BW - 1)) << 17);
}

__global__ __launch_bounds__(256) void k_bfin(const unsigned* __restrict__ tmp, const int* __restrict__ boff,
                                              int* __restrict__ ssrc, int* __restrict__ rp,
                                              float* __restrict__ dinv, int N){
  int b = blockIdx.x;
  int d0 = b << BSH;
  int lim = N - d0; if (lim > BW) lim = BW;
  __shared__ int dcnt[BW], dst_[BW], lfill[BW];
  int t = threadIdx.x;
  if (t < BW){ dcnt[t] = 0; lfill[t] = 0; }
  __syncthreads();
  int lo = boff[b], hi = boff[b + 1];
  for (int i = lo + t; i < hi; i += 256) atomicAdd(&dcnt[tmp[i] >> 17], 1);
  __syncthreads();
  if (t == 0){ int run = 0; for (int l = 0; l < BW; ++l){ dst_[l] = run; run += dcnt[l]; } }
  __syncthreads();
  if (t < lim){
    int d = d0 + t;
    rp[d] = lo + dst_[t];
    double dd = (double)(dcnt[t] + 1);           // +1 self-loop
    dinv[d] = (float)(1.0 / sqrt(dd));
  }
  __syncthreads();
  for (int i = lo + t; i < hi; i += 256){
    unsigned r = tmp[i];
    int l = r >> 17;
    int pos = dst_[l] + atomicAdd(&lfill[l], 1);
    ssrc[lo + pos] = (int)(r & 0x1FFFFu);
  }
}

// ---------------- GEMM: C[N,128] = (A[N,128] @ W[128,128]) * dinv[row] ----------------
// 256x128 tile, 256 threads, 16x8 register tile. k-sliced LDS (16 k's), global->reg
// prefetch of next tile overlapped with compute. DS:FMA = 6:128 per k -> VALU-bound.

__global__ __launch_bounds__(256, 2) void k_gemm(const float* __restrict__ A, const float* __restrict__ W,
                                                 const float* __restrict__ dinv,
                                                 float* __restrict__ C, int n){
  __shared__ __align__(16) float As[16][256];
  __shared__ __align__(16) float Ws[16][128];
  int t = threadIdx.x;
  int rg = t >> 4, cg = t & 15;
  int r0 = blockIdx.x * 256;
  int ra = rg * 16;
  int ca = cg * 4, cb = 64 + cg * 4;

  int grow = r0 + t; if (grow > n - 1) grow = n - 1;
  const float* ga = A + (size_t)grow * 128;

  float4 acc[16][2];
  #pragma unroll
  for (int j = 0; j < 16; ++j){ acc[j][0] = make_float4(0,0,0,0); acc[j][1] = make_float4(0,0,0,0); }

  // prefetch tile 0
  float4 a0 = *(const float4*)(ga + 0), a1 = *(const float4*)(ga + 4);
  float4 a2 = *(const float4*)(ga + 8), a3 = *(const float4*)(ga + 12);
  const float4* wsrc = (const float4*)W;
  float4 w0 = wsrc[t * 2], w1 = wsrc[t * 2 + 1];

  for (int k0 = 0; k0 < 128; k0 += 16){
    __syncthreads();
    As[ 0][t] = a0.x; As[ 1][t] = a0.y; As[ 2][t] = a0.z; As[ 3][t] = a0.w;
    As[ 4][t] = a1.x; As[ 5][t] = a1.y; As[ 6][t] = a1.z; As[ 7][t] = a1.w;
    As[ 8][t] = a2.x; As[ 9][t] = a2.y; As[10][t] = a2.z; As[11][t] = a2.w;
    As[12][t] = a3.x; As[13][t] = a3.y; As[14][t] = a3.z; As[15][t] = a3.w;
    ((float4*)Ws)[t * 2] = w0; ((float4*)Ws)[t * 2 + 1] = w1;
    __syncthreads();
    int k1 = k0 + 16;
    if (k1 < 128){
      a0 = *(const float4*)(ga + k1);     a1 = *(const float4*)(ga + k1 + 4);
      a2 = *(const float4*)(ga + k1 + 8); a3 = *(const float4*)(ga + k1 + 12);
      const float4* wn = (const float4*)(W + (size_t)k1 * 128);
      w0 = wn[t * 2]; w1 = wn[t * 2 + 1];
    }
    #pragma unroll
    for (int k = 0; k < 16; ++k){
      float4 av0 = *(const float4*)&As[k][ra];
      float4 av1 = *(const float4*)&As[k][ra + 4];
      float4 av2 = *(const float4*)&As[k][ra + 8];
      float4 av3 = *(const float4*)&As[k][ra + 12];
      float4 wa  = *(const float4*)&Ws[k][ca];
      float4 wb  = *(const float4*)&Ws[k][cb];
      float av[16] = {av0.x, av0.y, av0.z, av0.w, av1.x, av1.y, av1.z, av1.w,
                      av2.x, av2.y, av2.z, av2.w, av3.x, av3.y, av3.z, av3.w};
      #pragma unroll
      for (int j = 0; j < 16; ++j){
        acc[j][0].x += av[j] * wa.x; acc[j][0].y += av[j] * wa.y;
        acc[j][0].z += av[j] * wa.z; acc[j][0].w += av[j] * wa.w;
        acc[j][1].x += av[j] * wb.x; acc[j][1].y += av[j] * wb.y;
        acc[j][1].z += av[j] * wb.z; acc[j][1].w += av[j] * wb.w;
      }
    }
  }

  #pragma unroll
  for (int j = 0; j < 16; ++j){
    int rr = r0 + ra + j;
    if (rr < n){
      float sc = dinv[rr];
      float4 va = acc[j][0], vb = acc[j][1];
      va.x *= sc; va.y *= sc; va.z *= sc; va.w *= sc;
      vb.x *= sc; vb.y *= sc; vb.z *= sc; vb.w *= sc;
      *(float4*)(C + (size_t)rr * 128 + ca) = va;
      *(float4*)(C + (size_t)rr * 128 + cb) = vb;
    }
  }
}

// ---------------- aggregate: h_out = tanh(dinv[d]*(sum hw'[src] + hw'[d]) + b) ----------------
// one wave per (node, feature-half). Block b -> XCD b&7 (round-robin heuristic);
// F = (b&7)>=4 so XCDs 0-3 touch only the low 256B of each row, XCDs 4-7 the high 256B:
// halves per-XCD compulsory L2-miss footprint. Quarter-wave per edge (float4/lane,
// 16 lanes x 16B = 256B coalesced), 4 edges per instruction, 16-edge unroll.

__global__ __launch_bounds__(256) void k_agg(const float* __restrict__ hwp, const int* __restrict__ rp,
                                             const int* __restrict__ ssrc,
                                             const float* __restrict__ dinv, const float* __restrict__ bias,
                                             float* __restrict__ hout, int n){
  int b = blockIdx.x;
  int r = b & 7;
  int F = r >> 2;                       // feature half
  int s = (b >> 3) * 4 + (r & 3);       // slot of 4 nodes
  int node = s * 4 + (threadIdx.x >> 6);
  if (node >= n) return;
  int lane = threadIdx.x & 63;
  int ql = lane >> 4;                   // edge slot 0..3
  int fl = lane & 15;                   // feature quad within half
  const float4* base = (const float4*)hwp + F * 16 + fl;   // row stride = 32 float4

  int e0 = rp[node], e1 = rp[node + 1];
  float4 acc = make_float4(0, 0, 0, 0);
  for (int eb = e0; eb < e1; eb += 64){
    int m = e1 - eb; if (m > 64) m = 64;
    int sl = (lane < m) ? ssrc[eb + lane] : 0;
    int mp = m & ~3;
    int j = 0;
    for (; j + 16 <= mp; j += 16){
      int s0 = __shfl(sl, j + ql),     s1 = __shfl(sl, j + 4 + ql);
      int s2 = __shfl(sl, j + 8 + ql), s3 = __shfl(sl, j + 12 + ql);
      float4 v0 = base[(size_t)s0 * 32], v1 = base[(size_t)s1 * 32];
      float4 v2 = base[(size_t)s2 * 32], v3 = base[(size_t)s3 * 32];
      acc.x += v0.x; acc.y += v0.y; acc.z += v0.z; acc.w += v0.w;
      acc.x += v1.x; acc.y += v1.y; acc.z += v1.z; acc.w += v1.w;
      acc.x += v2.x; acc.y += v2.y; acc.z += v2.z; acc.w += v2.w;
      acc.x += v3.x; acc.y += v3.y; acc.z += v3.z; acc.w += v3.w;
    }
    if (j + 8 <= mp){
      int s0 = __shfl(sl, j + ql), s1 = __shfl(sl, j + 4 + ql);
      float4 v0 = base[(size_t)s0 * 32], v1 = base[(size_t)s1 * 32];
      acc.x += v0.x; acc.y += v0.y; acc.z += v0.z; acc.w += v0.w;
      acc.x += v1.x; acc.y += v1.y; acc.z += v1.z; acc.w += v1.w;
      j += 8;
    }
    if (j + 4 <= mp){
      int s0 = __shfl(sl, j + ql);
      float4 v0 = base[(size_t)s0 * 32];
      acc.x += v0.x; acc.y += v0.y; acc.z += v0.z; acc.w += v0.w;
      j += 4;
    }
    if (j < m){
      int s0 = __shfl(sl, j + ql);
      if (j + ql < m){
        float4 v0 = base[(size_t)s0 * 32];
        acc.x += v0.x; acc.y += v0.y; acc.z += v0.z; acc.w += v0.w;
      }
    }
  }
  // reduce across the 4 edge slots
  acc.x += __shfl_down(acc.x, 32); acc.y += __shfl_down(acc.y, 32);
  acc.z += __shfl_down(acc.z, 32); acc.w += __shfl_down(acc.w, 32);
  acc.x += __shfl_down(acc.x, 16); acc.y += __shfl_down(acc.y, 16);
  acc.z += __shfl_down(acc.z, 16); acc.w += __shfl_down(acc.w, 16);
  if (lane < 16){
    float4 vs = base[(size_t)node * 32];     // self term (already * dinv[node])
    acc.x += vs.x; acc.y += vs.y; acc.z += vs.z; acc.w += vs.w;
    float di = dinv[node];
    int f = F * 64 + fl * 4;
    float4 bv = *(const float4*)(bias + f);
    f4v rr;
    rr.x = tanhf(acc.x * di + bv.x);
    rr.y = tanhf(acc.y * di + bv.y);
    rr.z = tanhf(acc.z * di + bv.z);
    rr.w = tanhf(acc.w * di + bv.w);
    __builtin_nontemporal_store(rr, (f4v*)(hout + (size_t)node * 128 + f));
  }
}

// ---------------- pool: stage 1 partial max/sum ----------------

__global__ __launch_bounds__(256) void k_pool1(const float* __restrict__ h, const int* __restrict__ gstart,
                                               float* __restrict__ pmx, float* __restrict__ psm){
  int g = blockIdx.x >> 3, s = blockIdx.x & (PSPLIT - 1);
  int t = threadIdx.x, f = t & 127, half = t >> 7;
  int i0 = gstart[g], i1 = gstart[g + 1];
  int len = i1 - i0;
  int chunk = (len + PSPLIT - 1) / PSPLIT;
  int a = i0 + s * chunk;
  int b = a + chunk; if (b > i1) b = i1;

  float mx = -INFINITY, sm = 0.f;
  for (int i = a + half; i < b; i += 2){
    float v = h[(size_t)i * 128 + f];
    mx = fmaxf(mx, v); sm += v;
  }
  __shared__ float smx[128], ssm[128];
  if (half){ smx[f] = mx; ssm[f] = sm; }
  __syncthreads();
  if (!half){
    mx = fmaxf(mx, smx[f]); sm += ssm[f];
    pmx[(size_t)blockIdx.x * 128 + f] = mx;
    psm[(size_t)blockIdx.x * 128 + f] = sm;
  }
}

__global__ __launch_bounds__(128) void k_head(const float* __restrict__ pmx, const float* __restrict__ psm,
                                              const int* __restrict__ gstart,
                                              const float* __restrict__ Wl, const float* __restrict__ bl,
                                              float* __restrict__ out){
  int g = blockIdx.x, f = threadIdx.x;
  float mx = -INFINITY, sm = 0.f;
  #pragma unroll
  for (int s = 0; s < PSPLIT; ++s){
    mx = fmaxf(mx, pmx[((size_t)g * PSPLIT + s) * 128 + f]);
    sm += psm[((size_t)g * PSPLIT + s) * 128 + f];
  }
  int cnt = gstart[g + 1] - gstart[g];
  if (cnt <= 0) mx = 0.f;
  float mn = sm / (float)(cnt > 0 ? cnt : 1);
  float contrib = mx * Wl[f] + mn * Wl[128 + f];
  for (int o = 32; o > 0; o >>= 1) contrib += __shfl_down(contrib, o);
  __shared__ float sred[2];
  if ((f & 63) == 0) sred[f >> 6] = contrib;
  __syncthreads();
  if (f == 0) out[g] = sred[0] + sred[1] + bl[0];
}

// ---------------- launch ----------------

extern "C" void kernel_launch(void* const* d_in, const int* in_sizes, int n_in,
                              void* d_out, int out_size, void* d_ws, size_t ws_size,
                              hipStream_t stream){
  const float* x     = (const float*)d_in[0];
  const int*   ei    = (const int*)d_in[1];
  const int*   batch = (const int*)d_in[2];
  const float* W[4]  = {(const float*)d_in[3], (const float*)d_in[5], (const float*)d_in[7], (const float*)d_in[9]};
  const float* B[4]  = {(const float*)d_in[4], (const float*)d_in[6], (const float*)d_in[8], (const float*)d_in[10]};
  const float* Wl    = (const float*)d_in[11];
  const float* bl    = (const float*)d_in[12];
  float* out = (float*)d_out;

  int N = in_sizes[0] / 128;
  int E = in_sizes[1] / 2;
  int G = out_size;
  int NB = (N + BW - 1) >> BSH;

  char* ws = (char*)d_ws;
  size_t off = 0;
  auto alloc = [&](size_t bytes) -> void* {
    void* p = ws + off; off = align_up(off + bytes, 256); return p;
  };
  float* dinv  = (float*)alloc((size_t)N * 4);
  int*   rp    = (int*)  alloc((size_t)(N + 1) * 4);
  int*   bcnt  = (int*)  alloc((size_t)(NB + 1) * 4);
  int*   boff  = (int*)  alloc((size_t)(NB + 1) * 4);
  int*   bfill = (int*)  alloc((size_t)NB * 16 * 4);
  int*   gst   = (int*)  alloc((size_t)(G + 1) * 4);
  int*   ssrc  = (int*)  alloc((size_t)E * 4);
  float* pmx   = (float*)alloc((size_t)G * PSPLIT * 128 * 4);
  float* psm   = (float*)alloc((size_t)G * PSPLIT * 128 * 4);
  float* hw    = (float*)alloc((size_t)N * 128 * 4);
  float* h     = (float*)alloc((size_t)N * 128 * 4);
  unsigned* tmp = (unsigned*)hw;   // alias: tmp dead before first gemm writes hw

  hipMemsetAsync(bcnt, 0, (size_t)(NB + 1) * 4, stream);
  hipMemsetAsync(bfill, 0, (size_t)NB * 16 * 4, stream);

  int gE = (E + 255) / 256;
  k_bhist<<<128, 256, NB * 4, stream>>>(ei + E, bcnt, E, NB, batch, gst, N, G);
  k_bscan<<<1, 256, 0, stream>>>(bcnt, boff, NB, E, rp, N);
  k_bscat<<<gE, 256, 0, stream>>>(ei, boff, bfill, tmp, E);
  k_bfin <<<NB, 256, 0, stream>>>(tmp, boff, ssrc, rp, dinv, N);

  int gemmG = (N + 255) / 256;
  int slots = (N + 3) / 4;                 // (node-quad) slots per feature half
  int aggG  = 8 * ((slots + 3) / 4);       // XCD-steered grid
  const float* hin = x;
  for (int l = 0; l < 4; ++l){
    k_gemm<<<gemmG, 256, 0, stream>>>(hin, W[l], dinv, hw, N);
    k_agg <<<aggG, 256, 0, stream>>>(hw, rp, ssrc, dinv, B[l], h, N);
    hin = h;
  }
  k_pool1<<<G * PSPLIT, 256, 0, stream>>>(h, gst, pmx, psm);
  k_head <<<G, 128, 0, stream>>>(pmx, psm, gst, Wl, bl, out);
}

// Round 6
// 888.232 us; speedup vs baseline: 1.0598x; 1.0598x over previous
//
#include <hip/hip_runtime.h>
#include <math.h>

#define PSPLIT 8
#define BSH 5                  // bucket = dst >> BSH  (32 dsts/bucket)
#define BW 32

typedef float v4f __attribute__((ext_vector_type(4)));

static inline size_t align_up(size_t x, size_t a){ return (x + a - 1) & ~(a - 1); }

// ---------------- graph prep: bucketed CSR build ----------------

__global__ __launch_bounds__(256) void k_bhist(const int* __restrict__ col, int* __restrict__ bcnt,
                                               int E, int NB,
                                               const int* __restrict__ batch, int* __restrict__ gstart,
                                               int n, int G){
  extern __shared__ int lh[];
  for (int i = threadIdx.x; i < NB; i += 256) lh[i] = 0;
  __syncthreads();
  for (int e = blockIdx.x * 256 + threadIdx.x; e < E; e += gridDim.x * 256)
    atomicAdd(&lh[col[e] >> BSH], 1);
  __syncthreads();
  for (int i = threadIdx.x; i < NB; i += 256){
    int v = lh[i];
    if (v) atomicAdd(&bcnt[i], v);
  }
  // fused gstart
  for (int i = blockIdx.x * 256 + threadIdx.x; i < n; i += gridDim.x * 256){
    int cb = batch[i];
    if (i == 0){ for (int g = 0; g <= cb; ++g) gstart[g] = 0; }
    else { int pb = batch[i - 1]; for (int g = pb + 1; g <= cb; ++g) gstart[g] = i; }
    if (i == n - 1){ for (int g = cb + 1; g <= G; ++g) gstart[g] = n; }
  }
}

__global__ void k_bscan(const int* __restrict__ bcnt, int* __restrict__ boff, int NB, int E,
                        int* __restrict__ rp, int N){
  __shared__ int sd[256];
  int t = threadIdx.x;
  int c[16]; int s = 0;
  const int PT = (NB + 255) / 256;   // <= 16
  for (int j = 0; j < PT; ++j){ int i = t * PT + j; c[j] = (i < NB) ? bcnt[i] : 0; s += c[j]; }
  sd[t] = s; __syncthreads();
  for (int off = 1; off < 256; off <<= 1){
    int v = sd[t];
    if (t >= off) v += sd[t - off];
    __syncthreads(); sd[t] = v; __syncthreads();
  }
  int run = sd[t] - s;
  for (int j = 0; j < PT; ++j){ int i = t * PT + j; if (i < NB) boff[i] = run; run += c[j]; }
  if (t == 255){ boff[NB] = run; rp[N] = E; }
}

__global__ __launch_bounds__(256) void k_bscat(const int* __restrict__ ei, const int* __restrict__ boff,
                                               int* __restrict__ bfill, unsigned* __restrict__ tmp, int E){
  int e = blockIdx.x * 256 + threadIdx.x;
  if (e >= E) return;
  int s = ei[e], d = ei[E + e];
  int b = d >> BSH;
  int p = atomicAdd(&bfill[b * 16], 1);          // line-padded counter
  tmp[boff[b] + p] = (unsigned)s | ((unsigned)(d & (BW - 1)) << 17);
}

__global__ __launch_bounds__(256) void k_bfin(const unsigned* __restrict__ tmp, const int* __restrict__ boff,
                                              int* __restrict__ ssrc, int* __restrict__ rp,
                                              float* __restrict__ dinv, int N){
  int b = blockIdx.x;
  int d0 = b << BSH;
  int lim = N - d0; if (lim > BW) lim = BW;
  __shared__ int dcnt[BW], dst_[BW], lfill[BW];
  int t = threadIdx.x;
  if (t < BW){ dcnt[t] = 0; lfill[t] = 0; }
  __syncthreads();
  int lo = boff[b], hi = boff[b + 1];
  for (int i = lo + t; i < hi; i += 256) atomicAdd(&dcnt[tmp[i] >> 17], 1);
  __syncthreads();
  if (t == 0){ int run = 0; for (int l = 0; l < BW; ++l){ dst_[l] = run; run += dcnt[l]; } }
  __syncthreads();
  if (t < lim){
    int d = d0 + t;
    rp[d] = lo + dst_[t];
    double dd = (double)(dcnt[t] + 1);           // +1 self-loop
    dinv[d] = (float)(1.0 / sqrt(dd));
  }
  __syncthreads();
  for (int i = lo + t; i < hi; i += 256){
    unsigned r = tmp[i];
    int l = r >> 17;
    int pos = dst_[l] + atomicAdd(&lfill[l], 1);
    ssrc[lo + pos] = (int)(r & 0x1FFFFu);
  }
}

// ---------------- GEMM: C[N,128] = (A[N,128] @ W[128,128]) * dinv[row] ----------------
// 128x128 tile, 256 threads, 8x8 register tile, k-sliced LDS (16 k's), register
// double-buffer prefetch. v4f accumulate -> v_pk_fma_f32 (157 TF path, 2x scalar).

__global__ __launch_bounds__(256, 4) void k_gemm(const float* __restrict__ A, const float* __restrict__ W,
                                                 const float* __restrict__ dinv,
                                                 float* __restrict__ C, int n){
  __shared__ __align__(16) float As[16][128];
  __shared__ __align__(16) float Ws[16][128];
  int t = threadIdx.x;
  int rg = t >> 4, cg = t & 15;
  int r0 = blockIdx.x * 128;
  int ra = rg * 8;
  int ca = cg * 4, cb = 64 + cg * 4;

  // staging indices
  int srow = t >> 1;               // 0..127
  int shalf = (t & 1) * 8;         // 0 or 8
  int grow = r0 + srow; if (grow > n - 1) grow = n - 1;
  const float* ga = A + (size_t)grow * 128 + shalf;

  v4f acc_a[8], acc_b[8];
  #pragma unroll
  for (int j = 0; j < 8; ++j){ acc_a[j] = (v4f)(0.f); acc_b[j] = (v4f)(0.f); }

  // prefetch tile 0
  float4 a0 = *(const float4*)(ga + 0);
  float4 a1 = *(const float4*)(ga + 4);
  const float4* wsrc = (const float4*)W;
  float4 w0 = wsrc[t * 2], w1 = wsrc[t * 2 + 1];

  for (int k0 = 0; k0 < 128; k0 += 16){
    __syncthreads();
    As[shalf + 0][srow] = a0.x; As[shalf + 1][srow] = a0.y;
    As[shalf + 2][srow] = a0.z; As[shalf + 3][srow] = a0.w;
    As[shalf + 4][srow] = a1.x; As[shalf + 5][srow] = a1.y;
    As[shalf + 6][srow] = a1.z; As[shalf + 7][srow] = a1.w;
    ((float4*)Ws)[t * 2] = w0; ((float4*)Ws)[t * 2 + 1] = w1;
    __syncthreads();
    int k1 = k0 + 16;
    if (k1 < 128){
      a0 = *(const float4*)(ga + k1);
      a1 = *(const float4*)(ga + k1 + 4);
      const float4* wn = (const float4*)(W + (size_t)k1 * 128);
      w0 = wn[t * 2]; w1 = wn[t * 2 + 1];
    }
    #pragma unroll
    for (int k = 0; k < 16; ++k){
      v4f av0 = *(const v4f*)&As[k][ra];
      v4f av1 = *(const v4f*)&As[k][ra + 4];
      v4f wa  = *(const v4f*)&Ws[k][ca];
      v4f wb  = *(const v4f*)&Ws[k][cb];
      float av[8] = {av0.x, av0.y, av0.z, av0.w, av1.x, av1.y, av1.z, av1.w};
      #pragma unroll
      for (int j = 0; j < 8; ++j){
        acc_a[j] += av[j] * wa;      // v_pk_fma_f32 x2
        acc_b[j] += av[j] * wb;
      }
    }
  }

  #pragma unroll
  for (int j = 0; j < 8; ++j){
    int rr = r0 + ra + j;
    if (rr < n){
      float sc = dinv[rr];
      v4f va = acc_a[j] * sc, vb = acc_b[j] * sc;
      *(v4f*)(C + (size_t)rr * 128 + ca) = va;
      *(v4f*)(C + (size_t)rr * 128 + cb) = vb;
    }
  }
}

// ---------------- aggregate: h_out = tanh(dinv[d]*(sum hw'[src] + hw'[d]) + b) ----------------
// one wave per (node, feature-half); quarter-wave per edge (float4/lane, 256B coalesced
// per edge), 16-edge unroll, v4f pk-adds. Fabric-plateau bound (~3.8 TB/s).

__global__ __launch_bounds__(256) void k_agg(const float* __restrict__ hwp, const int* __restrict__ rp,
                                             const int* __restrict__ ssrc,
                                             const float* __restrict__ dinv, const float* __restrict__ bias,
                                             float* __restrict__ hout, int n){
  int b = blockIdx.x;
  int r = b & 7;
  int F = r >> 2;                       // feature half
  int s = (b >> 3) * 4 + (r & 3);       // slot of 4 nodes
  int node = s * 4 + (threadIdx.x >> 6);
  if (node >= n) return;
  int lane = threadIdx.x & 63;
  int ql = lane >> 4;                   // edge slot 0..3
  int fl = lane & 15;                   // feature quad within half
  const v4f* base = (const v4f*)hwp + F * 16 + fl;   // row stride = 32 v4f

  int e0 = rp[node], e1 = rp[node + 1];
  v4f acc = (v4f)(0.f);
  for (int eb = e0; eb < e1; eb += 64){
    int m = e1 - eb; if (m > 64) m = 64;
    int sl = (lane < m) ? ssrc[eb + lane] : 0;
    int mp = m & ~3;
    int j = 0;
    for (; j + 16 <= mp; j += 16){
      int s0 = __shfl(sl, j + ql),     s1 = __shfl(sl, j + 4 + ql);
      int s2 = __shfl(sl, j + 8 + ql), s3 = __shfl(sl, j + 12 + ql);
      v4f v0 = base[(size_t)s0 * 32], v1 = base[(size_t)s1 * 32];
      v4f v2 = base[(size_t)s2 * 32], v3 = base[(size_t)s3 * 32];
      acc += v0; acc += v1; acc += v2; acc += v3;
    }
    if (j + 8 <= mp){
      int s0 = __shfl(sl, j + ql), s1 = __shfl(sl, j + 4 + ql);
      v4f v0 = base[(size_t)s0 * 32], v1 = base[(size_t)s1 * 32];
      acc += v0; acc += v1;
      j += 8;
    }
    if (j + 4 <= mp){
      int s0 = __shfl(sl, j + ql);
      acc += base[(size_t)s0 * 32];
      j += 4;
    }
    if (j < m){
      int s0 = __shfl(sl, j + ql);
      if (j + ql < m){
        acc += base[(size_t)s0 * 32];
      }
    }
  }
  // reduce across the 4 edge slots
  acc.x += __shfl_down(acc.x, 32); acc.y += __shfl_down(acc.y, 32);
  acc.z += __shfl_down(acc.z, 32); acc.w += __shfl_down(acc.w, 32);
  acc.x += __shfl_down(acc.x, 16); acc.y += __shfl_down(acc.y, 16);
  acc.z += __shfl_down(acc.z, 16); acc.w += __shfl_down(acc.w, 16);
  if (lane < 16){
    acc += base[(size_t)node * 32];          // self term (already * dinv[node])
    float di = dinv[node];
    int f = F * 64 + fl * 4;
    v4f bv = *(const v4f*)(bias + f);
    v4f rr;
    rr.x = tanhf(acc.x * di + bv.x);
    rr.y = tanhf(acc.y * di + bv.y);
    rr.z = tanhf(acc.z * di + bv.z);
    rr.w = tanhf(acc.w * di + bv.w);
    __builtin_nontemporal_store(rr, (v4f*)(hout + (size_t)node * 128 + f));
  }
}

// ---------------- pool: stage 1 partial max/sum ----------------

__global__ __launch_bounds__(256) void k_pool1(const float* __restrict__ h, const int* __restrict__ gstart,
                                               float* __restrict__ pmx, float* __restrict__ psm){
  int g = blockIdx.x >> 3, s = blockIdx.x & (PSPLIT - 1);
  int t = threadIdx.x, f = t & 127, half = t >> 7;
  int i0 = gstart[g], i1 = gstart[g + 1];
  int len = i1 - i0;
  int chunk = (len + PSPLIT - 1) / PSPLIT;
  int a = i0 + s * chunk;
  int b = a + chunk; if (b > i1) b = i1;

  float mx = -INFINITY, sm = 0.f;
  for (int i = a + half; i < b; i += 2){
    float v = h[(size_t)i * 128 + f];
    mx = fmaxf(mx, v); sm += v;
  }
  __shared__ float smx[128], ssm[128];
  if (half){ smx[f] = mx; ssm[f] = sm; }
  __syncthreads();
  if (!half){
    mx = fmaxf(mx, smx[f]); sm += ssm[f];
    pmx[(size_t)blockIdx.x * 128 + f] = mx;
    psm[(size_t)blockIdx.x * 128 + f] = sm;
  }
}

__global__ __launch_bounds__(128) void k_head(const float* __restrict__ pmx, const float* __restrict__ psm,
                                              const int* __restrict__ gstart,
                                              const float* __restrict__ Wl, const float* __restrict__ bl,
                                              float* __restrict__ out){
  int g = blockIdx.x, f = threadIdx.x;
  float mx = -INFINITY, sm = 0.f;
  #pragma unroll
  for (int s = 0; s < PSPLIT; ++s){
    mx = fmaxf(mx, pmx[((size_t)g * PSPLIT + s) * 128 + f]);
    sm += psm[((size_t)g * PSPLIT + s) * 128 + f];
  }
  int cnt = gstart[g + 1] - gstart[g];
  if (cnt <= 0) mx = 0.f;
  float mn = sm / (float)(cnt > 0 ? cnt : 1);
  float contrib = mx * Wl[f] + mn * Wl[128 + f];
  for (int o = 32; o > 0; o >>= 1) contrib += __shfl_down(contrib, o);
  __shared__ float sred[2];
  if ((f & 63) == 0) sred[f >> 6] = contrib;
  __syncthreads();
  if (f == 0) out[g] = sred[0] + sred[1] + bl[0];
}

// ---------------- launch ----------------

extern "C" void kernel_launch(void* const* d_in, const int* in_sizes, int n_in,
                              void* d_out, int out_size, void* d_ws, size_t ws_size,
                              hipStream_t stream){
  const float* x     = (const float*)d_in[0];
  const int*   ei    = (const int*)d_in[1];
  const int*   batch = (const int*)d_in[2];
  const float* W[4]  = {(const float*)d_in[3], (const float*)d_in[5], (const float*)d_in[7], (const float*)d_in[9]};
  const float* B[4]  = {(const float*)d_in[4], (const float*)d_in[6], (const float*)d_in[8], (const float*)d_in[10]};
  const float* Wl    = (const float*)d_in[11];
  const float* bl    = (const float*)d_in[12];
  float* out = (float*)d_out;

  int N = in_sizes[0] / 128;
  int E = in_sizes[1] / 2;
  int G = out_size;
  int NB = (N + BW - 1) >> BSH;

  char* ws = (char*)d_ws;
  size_t off = 0;
  auto alloc = [&](size_t bytes) -> void* {
    void* p = ws + off; off = align_up(off + bytes, 256); return p;
  };
  float* dinv  = (float*)alloc((size_t)N * 4);
  int*   rp    = (int*)  alloc((size_t)(N + 1) * 4);
  int*   bcnt  = (int*)  alloc((size_t)(NB + 1) * 4);
  int*   boff  = (int*)  alloc((size_t)(NB + 1) * 4);
  int*   bfill = (int*)  alloc((size_t)NB * 16 * 4);
  int*   gst   = (int*)  alloc((size_t)(G + 1) * 4);
  int*   ssrc  = (int*)  alloc((size_t)E * 4);
  float* pmx   = (float*)alloc((size_t)G * PSPLIT * 128 * 4);
  float* psm   = (float*)alloc((size_t)G * PSPLIT * 128 * 4);
  float* hw    = (float*)alloc((size_t)N * 128 * 4);
  float* h     = (float*)alloc((size_t)N * 128 * 4);
  unsigned* tmp = (unsigned*)hw;   // alias: tmp dead before first gemm writes hw

  hipMemsetAsync(bcnt, 0, (size_t)(NB + 1) * 4, stream);
  hipMemsetAsync(bfill, 0, (size_t)NB * 16 * 4, stream);

  int gE = (E + 255) / 256;
  k_bhist<<<128, 256, NB * 4, stream>>>(ei + E, bcnt, E, NB, batch, gst, N, G);
  k_bscan<<<1, 256, 0, stream>>>(bcnt, boff, NB, E, rp, N);
  k_bscat<<<gE, 256, 0, stream>>>(ei, boff, bfill, tmp, E);
  k_bfin <<<NB, 256, 0, stream>>>(tmp, boff, ssrc, rp, dinv, N);

  int gemmG = (N + 127) / 128;
  int slots = (N + 3) / 4;                 // (node-quad) slots per feature half
  int aggG  = 8 * ((slots + 3) / 4);       // XCD-steered grid
  const float* hin = x;
  for (int l = 0; l < 4; ++l){
    k_gemm<<<gemmG, 256, 0, stream>>>(hin, W[l], dinv, hw, N);
    k_agg <<<aggG, 256, 0, stream>>>(hw, rp, ssrc, dinv, B[l], h, N);
    hin = h;
  }
  k_pool1<<<G * PSPLIT, 256, 0, stream>>>(h, gst, pmx, psm);
  k_head <<<G, 128, 0, stream>>>(pmx, psm, gst, Wl, bl, out);
}